// Round 1
// baseline (859.244 us; speedup 1.0000x reference)
//
#include <hip/hip_runtime.h>
#include <hip/hip_bf16.h>

#define Bn 4
#define Sn 2048
#define Hn 8
#define Dn 64
#define En 512

typedef __attribute__((ext_vector_type(8))) short short8v;
typedef __attribute__((ext_vector_type(4))) float float4v;

__device__ __forceinline__ short f2bf(float x){
    __hip_bfloat16 h = __float2bfloat16(x);
    return *reinterpret_cast<short*>(&h);
}
__device__ __forceinline__ float bf2f(short s){
    union { unsigned int u; float f; } c;
    c.u = ((unsigned int)(unsigned short)s) << 16;
    return c.f;
}

// ---------------- Wo fp32 -> bf16 ----------------
__global__ __launch_bounds__(256) void wo_cvt_kernel(const float* __restrict__ Wo,
                                                     short* __restrict__ Wob){
    int i = (blockIdx.x * 256 + threadIdx.x) * 4;
    float4 v = *(const float4*)(Wo + i);
    short4 o;
    o.x = f2bf(v.x); o.y = f2bf(v.y); o.z = f2bf(v.z); o.w = f2bf(v.w);
    *(short4*)(Wob + i) = o;
}

// ---------------- per-head input projections ----------------
// blockIdx.z: 0: values*Wv -> Vt[bh][d][k] (transposed); 1: keys*Wk -> Kp[bh][k][d]; 2: query*Wq -> Qp[bh][q][d]
__global__ __launch_bounds__(256) void proj_kernel(
    const float* __restrict__ values, const float* __restrict__ keys, const float* __restrict__ query,
    const float* __restrict__ Wv, const float* __restrict__ Wk, const float* __restrict__ Wq,
    short* __restrict__ Qp, short* __restrict__ Kp, short* __restrict__ Vt)
{
    const int sel = blockIdx.z;
    const float* X = (sel == 0) ? values : ((sel == 1) ? keys : query);
    const float* W = (sel == 0) ? Wv : ((sel == 1) ? Wk : Wq);
    const int bh = blockIdx.y;
    const int b = bh >> 3, h = bh & 7;
    const int s0 = blockIdx.x * 64;
    const int wave = threadIdx.x >> 6;
    const int lane = threadIdx.x & 63;
    const int l16 = lane & 15, quad = lane >> 4;

    // B-fragments: B[k=d][n=e], lane holds e=t*16+l16, d=st*32+quad*8+j (contiguous in W rows)
    short8v bw[4][2];
    #pragma unroll
    for (int t = 0; t < 4; t++){
      #pragma unroll
      for (int st = 0; st < 2; st++){
        const float* wp = W + (t*16 + l16)*64 + st*32 + quad*8;
        float4 w0 = *(const float4*)(wp);
        float4 w1 = *(const float4*)(wp + 4);
        short8v f;
        f[0]=f2bf(w0.x); f[1]=f2bf(w0.y); f[2]=f2bf(w0.z); f[3]=f2bf(w0.w);
        f[4]=f2bf(w1.x); f[5]=f2bf(w1.y); f[6]=f2bf(w1.z); f[7]=f2bf(w1.w);
        bw[t][st] = f;
      }
    }

    const int row = s0 + wave*16 + l16;
    short8v fa[2];
    #pragma unroll
    for (int st = 0; st < 2; st++){
        const float* xp = X + ((size_t)b*Sn + row)*En + h*Dn + st*32 + quad*8;
        float4 x0 = *(const float4*)(xp);
        float4 x1 = *(const float4*)(xp + 4);
        short8v f;
        f[0]=f2bf(x0.x); f[1]=f2bf(x0.y); f[2]=f2bf(x0.z); f[3]=f2bf(x0.w);
        f[4]=f2bf(x1.x); f[5]=f2bf(x1.y); f[6]=f2bf(x1.z); f[7]=f2bf(x1.w);
        fa[st] = f;
    }

    const int rbase = s0 + wave*16 + quad*4;   // C/D: row=quad*4+reg, col=l16
    if (sel == 0){
        #pragma unroll
        for (int t = 0; t < 4; t++){
            float4v a = {0.f,0.f,0.f,0.f};
            a = __builtin_amdgcn_mfma_f32_16x16x32_bf16(fa[0], bw[t][0], a, 0,0,0);
            a = __builtin_amdgcn_mfma_f32_16x16x32_bf16(fa[1], bw[t][1], a, 0,0,0);
            int e = t*16 + l16;
            short4 pk;
            pk.x = f2bf(a[0]); pk.y = f2bf(a[1]); pk.z = f2bf(a[2]); pk.w = f2bf(a[3]);
            *(short4*)(Vt + ((size_t)bh*Dn + e)*Sn + rbase) = pk;   // 4 consecutive k
        }
    } else {
        short* dst = (sel == 1) ? Kp : Qp;
        #pragma unroll
        for (int t = 0; t < 4; t++){
            float4v a = {0.f,0.f,0.f,0.f};
            a = __builtin_amdgcn_mfma_f32_16x16x32_bf16(fa[0], bw[t][0], a, 0,0,0);
            a = __builtin_amdgcn_mfma_f32_16x16x32_bf16(fa[1], bw[t][1], a, 0,0,0);
            int e = t*16 + l16;
            #pragma unroll
            for (int r = 0; r < 4; r++)
                dst[((size_t)bh*Sn + rbase + r)*Dn + e] = f2bf(a[r]);
        }
    }
}

// ---------------- fused scores + softmax + attention write + PV ----------------
__global__ __launch_bounds__(256) void attn_kernel(
    const short* __restrict__ Qp, const short* __restrict__ Kp, const short* __restrict__ Vt,
    const int* __restrict__ mask, float* __restrict__ attn, short* __restrict__ Obf)
{
    // 16 q-rows x 2048 keys of unnormalized exp(score), bf16, +8 pad (2-way-free banks)
    __shared__ short sc[16][2056];
    __shared__ float wsum[4][16];
    __shared__ float vinv[16];

    const int qt = blockIdx.x, h = blockIdx.y, b = blockIdx.z;
    const int bh = b*Hn + h;
    const int tid = threadIdx.x;
    const int wave = tid >> 6, lane = tid & 63;
    const int l16 = lane & 15, quad = lane >> 4;
    const int q0 = qt * 16;

    const short* Qbase = Qp + (size_t)bh*Sn*Dn;
    const short* Kbase = Kp + (size_t)bh*Sn*Dn;
    const short* Vbase = Vt + (size_t)bh*Dn*Sn;

    // A-fragments for this q-tile (reused over all key tiles)
    short8v qa0 = *(const short8v*)(Qbase + (q0 + l16)*Dn + quad*8);
    short8v qa1 = *(const short8v*)(Qbase + (q0 + l16)*Dn + 32 + quad*8);

    const float SCALE = 0.0441941738241592f;   // 1/sqrt(512)
    float rs0=0.f, rs1=0.f, rs2=0.f, rs3=0.f;
    const int kw = wave * 512;                 // this wave's key chunk
    const int km = b*Sn;
    for (int t = 0; t < 32; t++){
        const int k0 = kw + t*16;
        short8v kb0 = *(const short8v*)(Kbase + (k0 + l16)*Dn + quad*8);
        short8v kb1 = *(const short8v*)(Kbase + (k0 + l16)*Dn + 32 + quad*8);
        float4v a = {0.f,0.f,0.f,0.f};
        a = __builtin_amdgcn_mfma_f32_16x16x32_bf16(qa0, kb0, a, 0,0,0);
        a = __builtin_amdgcn_mfma_f32_16x16x32_bf16(qa1, kb1, a, 0,0,0);
        const int mk = mask[km + k0 + l16];
        const int col = k0 + l16;
        // |score| <= ~3 -> exp without max-subtraction is safe; masked -> exactly 0
        float p0 = (mk != 0) ? __expf(a[0]*SCALE) : 0.f;
        float p1 = (mk != 0) ? __expf(a[1]*SCALE) : 0.f;
        float p2 = (mk != 0) ? __expf(a[2]*SCALE) : 0.f;
        float p3 = (mk != 0) ? __expf(a[3]*SCALE) : 0.f;
        rs0 += p0; rs1 += p1; rs2 += p2; rs3 += p3;
        sc[quad*4 + 0][col] = f2bf(p0);
        sc[quad*4 + 1][col] = f2bf(p1);
        sc[quad*4 + 2][col] = f2bf(p2);
        sc[quad*4 + 3][col] = f2bf(p3);
    }
    // per-quad (16-lane) row-sum reduction
    #pragma unroll
    for (int off = 1; off < 16; off <<= 1){
        rs0 += __shfl_xor(rs0, off);
        rs1 += __shfl_xor(rs1, off);
        rs2 += __shfl_xor(rs2, off);
        rs3 += __shfl_xor(rs3, off);
    }
    if (l16 == 0){
        wsum[wave][quad*4 + 0] = rs0;
        wsum[wave][quad*4 + 1] = rs1;
        wsum[wave][quad*4 + 2] = rs2;
        wsum[wave][quad*4 + 3] = rs3;
    }
    __syncthreads();
    if (tid < 16){
        float s = wsum[0][tid] + wsum[1][tid] + wsum[2][tid] + wsum[3][tid];
        vinv[tid] = (s > 0.f) ? 1.f/s : 0.f;
    }
    __syncthreads();

    // ---- write normalized attention (fp32, streaming stores, fully coalesced) ----
    float* arow = attn + (size_t)bh*Sn*Sn + (size_t)q0*Sn;
    for (int row = 0; row < 16; row++){
        const float sr = vinv[row];
        short8v v8 = *(const short8v*)(&sc[row][tid*8]);
        float4v o0, o1;
        o0[0]=bf2f(v8[0])*sr; o0[1]=bf2f(v8[1])*sr; o0[2]=bf2f(v8[2])*sr; o0[3]=bf2f(v8[3])*sr;
        o1[0]=bf2f(v8[4])*sr; o1[1]=bf2f(v8[5])*sr; o1[2]=bf2f(v8[6])*sr; o1[3]=bf2f(v8[7])*sr;
        float* dst = arow + (size_t)row*Sn + tid*8;
        __builtin_nontemporal_store(o0, (float4v*)dst);
        __builtin_nontemporal_store(o1, (float4v*)(dst + 4));
    }

    // ---- P @ V over this wave's 512-key chunk (unnormalized, scale at end) ----
    float4v oacc0 = {0.f,0.f,0.f,0.f}, oacc1 = {0.f,0.f,0.f,0.f},
            oacc2 = {0.f,0.f,0.f,0.f}, oacc3 = {0.f,0.f,0.f,0.f};
    for (int ks = 0; ks < 16; ks++){
        const int kb = kw + ks*32 + quad*8;
        short8v pa  = *(const short8v*)(&sc[l16][kb]);
        short8v vb0 = *(const short8v*)(Vbase + (size_t)( 0 + l16)*Sn + kb);
        short8v vb1 = *(const short8v*)(Vbase + (size_t)(16 + l16)*Sn + kb);
        short8v vb2 = *(const short8v*)(Vbase + (size_t)(32 + l16)*Sn + kb);
        short8v vb3 = *(const short8v*)(Vbase + (size_t)(48 + l16)*Sn + kb);
        oacc0 = __builtin_amdgcn_mfma_f32_16x16x32_bf16(pa, vb0, oacc0, 0,0,0);
        oacc1 = __builtin_amdgcn_mfma_f32_16x16x32_bf16(pa, vb1, oacc1, 0,0,0);
        oacc2 = __builtin_amdgcn_mfma_f32_16x16x32_bf16(pa, vb2, oacc2, 0,0,0);
        oacc3 = __builtin_amdgcn_mfma_f32_16x16x32_bf16(pa, vb3, oacc3, 0,0,0);
    }
    __syncthreads();                 // all waves done reading sc
    float* osc = (float*)&sc[0][0];  // alias: 4 waves x 16x64 fp32 partials (16 KB)
    {
        const int rb = quad*4;
        #pragma unroll
        for (int r = 0; r < 4; r++){
            osc[wave*1024 + (rb + r)*64 +  0 + l16] = oacc0[r];
            osc[wave*1024 + (rb + r)*64 + 16 + l16] = oacc1[r];
            osc[wave*1024 + (rb + r)*64 + 32 + l16] = oacc2[r];
            osc[wave*1024 + (rb + r)*64 + 48 + l16] = oacc3[r];
        }
    }
    __syncthreads();
    #pragma unroll
    for (int i = 0; i < 4; i++){
        const int id = tid + i*256;
        const int row = id >> 6, d = id & 63;
        float v = osc[id] + osc[1024 + id] + osc[2048 + id] + osc[3072 + id];
        v *= vinv[row];
        Obf[((size_t)b*Sn + q0 + row)*En + h*Dn + d] = f2bf(v);
    }
}

// ---------------- out = O @ Wo^T + bo  (8192 x 512 x 512, bf16 MFMA) ----------------
__global__ __launch_bounds__(256) void outproj_kernel(
    const short* __restrict__ Obf, const short* __restrict__ Wob,
    const float* __restrict__ bo, float* __restrict__ out)
{
    const int nt = blockIdx.x;     // 8 col tiles of 64
    const int mt = blockIdx.y;     // 128 row tiles of 64
    const int wave = threadIdx.x >> 6, lane = threadIdx.x & 63;
    const int l16 = lane & 15, quad = lane >> 4;
    const int m0 = mt*64 + wave*16;
    const int n0 = nt*64;

    float4v acc0 = {0.f,0.f,0.f,0.f}, acc1 = {0.f,0.f,0.f,0.f},
            acc2 = {0.f,0.f,0.f,0.f}, acc3 = {0.f,0.f,0.f,0.f};
    for (int ks = 0; ks < 16; ks++){
        const int kb = ks*32 + quad*8;
        short8v af = *(const short8v*)(Obf + (size_t)(m0 + l16)*En + kb);
        short8v b0 = *(const short8v*)(Wob + (size_t)(n0 +  0 + l16)*En + kb);
        short8v b1 = *(const short8v*)(Wob + (size_t)(n0 + 16 + l16)*En + kb);
        short8v b2 = *(const short8v*)(Wob + (size_t)(n0 + 32 + l16)*En + kb);
        short8v b3 = *(const short8v*)(Wob + (size_t)(n0 + 48 + l16)*En + kb);
        acc0 = __builtin_amdgcn_mfma_f32_16x16x32_bf16(af, b0, acc0, 0,0,0);
        acc1 = __builtin_amdgcn_mfma_f32_16x16x32_bf16(af, b1, acc1, 0,0,0);
        acc2 = __builtin_amdgcn_mfma_f32_16x16x32_bf16(af, b2, acc2, 0,0,0);
        acc3 = __builtin_amdgcn_mfma_f32_16x16x32_bf16(af, b3, acc3, 0,0,0);
    }
    #pragma unroll
    for (int t = 0; t < 4; t++){
        float4v a = (t==0)?acc0:((t==1)?acc1:((t==2)?acc2:acc3));
        const int e = n0 + t*16 + l16;
        const float bias = bo[e];
        #pragma unroll
        for (int r = 0; r < 4; r++)
            out[(size_t)(m0 + quad*4 + r)*En + e] = a[r] + bias;
    }
}

extern "C" void kernel_launch(void* const* d_in, const int* in_sizes, int n_in,
                              void* d_out, int out_size, void* d_ws, size_t ws_size,
                              hipStream_t stream)
{
    const float* values = (const float*)d_in[0];
    const float* keys   = (const float*)d_in[1];
    const float* query  = (const float*)d_in[2];
    const int*   mask   = (const int*)d_in[3];
    const float* Wv = (const float*)d_in[4];
    const float* Wk = (const float*)d_in[5];
    const float* Wq = (const float*)d_in[6];
    const float* Wo = (const float*)d_in[7];
    const float* bo = (const float*)d_in[8];

    float* out  = (float*)d_out;
    float* attn = out + (size_t)Bn*Sn*En;   // outputs concatenated: out, then attention

    short* Qp  = (short*)d_ws;                       // [bh][s][64] bf16
    short* Kp  = Qp + (size_t)Bn*Hn*Sn*Dn;           // [bh][k][64] bf16
    short* Vt  = Kp + (size_t)Bn*Hn*Sn*Dn;           // [bh][64][k] bf16 (transposed)
    short* Obf = Vt + (size_t)Bn*Hn*Sn*Dn;           // [b*s][512] bf16
    short* Wob = Obf + (size_t)Bn*Sn*En;             // [512][512] bf16

    wo_cvt_kernel<<<dim3((En*En)/1024), 256, 0, stream>>>(Wo, Wob);
    proj_kernel<<<dim3(Sn/64, Bn*Hn, 3), 256, 0, stream>>>(values, keys, query, Wv, Wk, Wq, Qp, Kp, Vt);
    attn_kernel<<<dim3(Sn/16, Hn, Bn), 256, 0, stream>>>(Qp, Kp, Vt, mask, attn, Obf);
    outproj_kernel<<<dim3(En/64, (Bn*Sn)/64), 256, 0, stream>>>(Obf, Wob, bo, out);
}